// Round 6
// baseline (284.713 us; speedup 1.0000x reference)
//
#include <hip/hip_runtime.h>
#include <math.h>

// CapsuleLayer fused, round 6: revert to proven round-2 structure, plus
//  (1) hi-only B: GEMM = (xh+xl)*wh, 2 MFMA/tile, 8KB/ks staging images
//  (2) nontemporal x loads / out stores
// Everything else identical to the round-2 kernel that passed (261 us).

#define BATCH 131072
#define DDIM  768
#define NC    5
#define NPD   16
#define BM    64
#define NKS   24

typedef __attribute__((ext_vector_type(8))) short short8;
typedef __attribute__((ext_vector_type(4))) float f32x4;

// W (routing transform) LDS layout, skewed by p*4 floats (round-1/2 proven)
#define WLDS(p,c,i) ((((p)*NC+(c))*NPD+(i))*16 + (p)*4)
#define UA_OFF    10272
#define UA_STRIDE 136
#define SMEM_FLOATS (UA_OFF + 16*UA_STRIDE)   // 12448 floats = 49792 B

__device__ __forceinline__ unsigned short f2b_rne(float f) {
    unsigned u = __builtin_bit_cast(unsigned, f);
    u += 0x7fffu + ((u >> 16) & 1u);
    return (unsigned short)(u >> 16);
}
__device__ __forceinline__ float b2f(unsigned short h) {
    unsigned u = ((unsigned)h) << 16;
    return __builtin_bit_cast(float, u);
}
template<int CTRL>
__device__ __forceinline__ float dpp_add(float v) {
    int s = __builtin_amdgcn_update_dpp(0, __builtin_bit_cast(int, v),
                                        CTRL, 0xf, 0xf, false);
    return v + __builtin_bit_cast(float, s);
}
__device__ __forceinline__ float rowsum16(float v) {  // sum over 16-lane dpp row
    v = dpp_add<0x121>(v); v = dpp_add<0x122>(v);
    v = dpp_add<0x124>(v); v = dpp_add<0x128>(v);
    return v;
}
__device__ __forceinline__ float rowsum8(float v) {   // sum over 8 same-parity lanes
    v = dpp_add<0x122>(v); v = dpp_add<0x124>(v); v = dpp_add<0x128>(v);
    return v;
}
__device__ __forceinline__ float pairsum(float v) { return dpp_add<0xB1>(v); }

// ---- prep: Wp hi-bf16 frag images, 4096 shorts (8KB) per K-step ----------
__global__ void caps_prep_wp(const float* __restrict__ Wp,
                             unsigned short* __restrict__ wpt) {
    const int idx = blockIdx.x * 256 + threadIdx.x;   // 384 blocks -> 98304
    const int ks  = idx >> 12;
    const int r   = idx & 4095;
    const int col = r >> 5;       // p*16+o
    const int k   = r & 31;
    wpt[ks * 4096 + col * 32 + k] =
        f2b_rne(Wp[(col >> 4) * (DDIM * NPD) + (ks * 32 + k) * NPD + (col & 15)]);
}

// ---- main ----------------------------------------------------------------
__global__ __launch_bounds__(256, 3)
void caps_main(const float* __restrict__ x, const float* __restrict__ bp,
               const float* __restrict__ Wg,
               const unsigned short* __restrict__ wpt,
               float* __restrict__ out)
{
    __shared__ float smf[SMEM_FLOATS];
    char* smc = (char*)smf;
    const int tid  = threadIdx.x;
    const int w    = tid >> 6;
    const int lane = tid & 63;
    const int ln   = lane & 15;
    const int g    = lane >> 4;
    const int b0   = blockIdx.x * BM;

    f32x4 acc[8];
#pragma unroll
    for (int t = 0; t < 8; ++t) acc[t] = (f32x4){0.f, 0.f, 0.f, 0.f};

    const float* xrow = x + (size_t)(b0 + w * 16 + ln) * DDIM + g * 8;
    const char*  wptc = (const char*)wpt;

    // prologue: stage ks=0 (8192 B image)
    f32x4 sa = *(const f32x4*)(wptc + tid * 32);
    f32x4 sb = *(const f32x4*)(wptc + tid * 32 + 16);
    f32x4 xa = __builtin_nontemporal_load((const f32x4*)xrow);
    f32x4 xb = __builtin_nontemporal_load((const f32x4*)(xrow + 4));
    *(f32x4*)(smc + tid * 32)      = sa;
    *(f32x4*)(smc + tid * 32 + 16) = sb;
    __syncthreads();

    for (int ks = 0; ks < NKS; ++ks) {
        const char* cur = smc + (ks & 1) * 8192;
        char*       nxt = smc + ((ks + 1) & 1) * 8192;
        f32x4 nxa, nxb;
        if (ks < NKS - 1) {
            const char* wim = wptc + (size_t)(ks + 1) * 8192;
            sa = *(const f32x4*)(wim + tid * 32);
            sb = *(const f32x4*)(wim + tid * 32 + 16);
            nxa = __builtin_nontemporal_load((const f32x4*)(xrow + (ks + 1) * 32));
            nxb = __builtin_nontemporal_load((const f32x4*)(xrow + (ks + 1) * 32 + 4));
        }
        // A frags: fp32 -> bf16 hi/lo (round-2 proven scalar path)
        const float av[8] = {xa[0], xa[1], xa[2], xa[3], xb[0], xb[1], xb[2], xb[3]};
        short8 ah, al;
#pragma unroll
        for (int e = 0; e < 8; ++e) {
            const unsigned short h = f2b_rne(av[e]);
            ah[e] = (short)h;
            al[e] = (short)f2b_rne(av[e] - b2f(h));
        }
#pragma unroll
        for (int t = 0; t < 8; ++t) {
            const short8 bh = *(const short8*)(cur + (t * 16 + ln) * 64 + g * 16);
            acc[t] = __builtin_amdgcn_mfma_f32_16x16x32_bf16(ah, bh, acc[t], 0, 0, 0);
            acc[t] = __builtin_amdgcn_mfma_f32_16x16x32_bf16(al, bh, acc[t], 0, 0, 0);
        }
        if (ks < NKS - 1) {
            *(f32x4*)(nxt + tid * 32)      = sa;
            *(f32x4*)(nxt + tid * 32 + 16) = sb;
            xa = nxa; xb = nxb;
        }
        __syncthreads();
    }

    // load routing transform W (fp32, skewed) into LDS [0, 41088) bytes
    {
        const f32x4* wg4 = (const f32x4*)Wg;
#pragma unroll
        for (int q = 0; q < 10; ++q) {
            const int f4i  = q * 256 + tid;      // < 2560
            const int flat = f4i * 4;
            const int p    = flat / 1280;
            f32x4 wv = wg4[f4i];
            *(f32x4*)&smf[flat + p * 4] = wv;
        }
    }

    // phase-2 thread roles (round-2 proven)
    const int tm = tid >> 4, tn = tid & 15;
    const int pp = tn >> 1, jh = tn & 1, j0 = jh * 8;
    float bb[16];
#pragma unroll
    for (int q = 0; q < 4; ++q) {
        f32x4 b4 = *(const f32x4*)(bp + pp * NPD + q * 4);
        bb[q * 4 + 0] = b4[0]; bb[q * 4 + 1] = b4[1];
        bb[q * 4 + 2] = b4[2]; bb[q * 4 + 3] = b4[3];
    }
    float* uA = smf + UA_OFF;

    for (int p = 0; p < 4; ++p) {
        // every wave dumps acc[*][p] (rows == p mod 4 of its 16-row tile)
#pragma unroll
        for (int pc = 0; pc < 4; ++pc) if (pc == p) {
#pragma unroll
            for (int t = 0; t < 8; ++t)
                uA[(w * 4 + g) * UA_STRIDE + t * 16 + ln] = acc[t][pc];
        }
        __syncthreads();

        // ---- one row per thread ----
        float u[16];
#pragma unroll
        for (int q = 0; q < 4; ++q) {
            f32x4 u4 = *(const f32x4*)&uA[tm * UA_STRIDE + pp * NPD + q * 4];
            u[q * 4 + 0] = u4[0] + bb[q * 4 + 0];
            u[q * 4 + 1] = u4[1] + bb[q * 4 + 1];
            u[q * 4 + 2] = u4[2] + bb[q * 4 + 2];
            u[q * 4 + 3] = u4[3] + bb[q * 4 + 3];
        }
        float sq = 0.f;
#pragma unroll
        for (int q = 0; q < 16; ++q) sq = fmaf(u[q], u[q], sq);
        const float scl = (sq / (1.f + sq)) * (1.f / (sqrtf(sq) + 1e-8f));
#pragma unroll
        for (int q = 0; q < 16; ++q) u[q] *= scl;

        // votes u_hat (registers), W from LDS (4-way broadcast across tm)
        float uh[NC][8];
#pragma unroll
        for (int c = 0; c < NC; ++c) {
#pragma unroll
            for (int jj = 0; jj < 8; ++jj) uh[c][jj] = 0.f;
#pragma unroll
            for (int q = 0; q < 16; ++q) {
                const float* wr = &smf[WLDS(pp, c, q) + j0];
                f32x4 w0 = *(const f32x4*)(wr);
                f32x4 w1 = *(const f32x4*)(wr + 4);
                const float uq = u[q];
                uh[c][0] = fmaf(uq, w0[0], uh[c][0]);
                uh[c][1] = fmaf(uq, w0[1], uh[c][1]);
                uh[c][2] = fmaf(uq, w0[2], uh[c][2]);
                uh[c][3] = fmaf(uq, w0[3], uh[c][3]);
                uh[c][4] = fmaf(uq, w1[0], uh[c][4]);
                uh[c][5] = fmaf(uq, w1[1], uh[c][5]);
                uh[c][6] = fmaf(uq, w1[2], uh[c][6]);
                uh[c][7] = fmaf(uq, w1[3], uh[c][7]);
            }
        }

        // dynamic routing, 3 iterations (DPP reductions)
        float blog[NC] = {0.f, 0.f, 0.f, 0.f, 0.f};
        float s[NC][8];
#pragma unroll
        for (int itr = 0; itr < 3; ++itr) {
            float m = blog[0];
#pragma unroll
            for (int c = 1; c < NC; ++c) m = fmaxf(m, blog[c]);
            float e[NC]; float es = 0.f;
#pragma unroll
            for (int c = 0; c < NC; ++c) { e[c] = __expf(blog[c] - m); es += e[c]; }
            const float inv = 1.f / es;
#pragma unroll
            for (int c = 0; c < NC; ++c) {
                const float cc = e[c] * inv;
#pragma unroll
                for (int jj = 0; jj < 8; ++jj) s[c][jj] = cc * uh[c][jj];
            }
#pragma unroll
            for (int c = 0; c < NC; ++c)
#pragma unroll
                for (int jj = 0; jj < 8; ++jj) s[c][jj] = rowsum8(s[c][jj]);
#pragma unroll
            for (int c = 0; c < NC; ++c) {
                float ss = 0.f;
#pragma unroll
                for (int jj = 0; jj < 8; ++jj) ss = fmaf(s[c][jj], s[c][jj], ss);
                ss = pairsum(ss);
                const float vs = (ss / (1.f + ss)) * (1.f / (sqrtf(ss) + 1e-8f));
#pragma unroll
                for (int jj = 0; jj < 8; ++jj) s[c][jj] *= vs;
            }
            if (itr < 2) {
#pragma unroll
                for (int c = 0; c < NC; ++c) {
                    float a = 0.f;
#pragma unroll
                    for (int jj = 0; jj < 8; ++jj) a = fmaf(uh[c][jj], s[c][jj], a);
                    a = pairsum(a);
                    blog[c] += a;
                }
            }
        }

        if (pp < NC) {
            float o[8];
#pragma unroll
            for (int jj = 0; jj < 8; ++jj) o[jj] = s[0][jj];
#pragma unroll
            for (int c = 1; c < NC; ++c) {
                const bool sel = (pp == c);
#pragma unroll
                for (int jj = 0; jj < 8; ++jj) o[jj] = sel ? s[c][jj] : o[jj];
            }
            const int row_glob = b0 + (tm >> 2) * 16 + (tm & 3) * 4 + p;
            float* og = out + (size_t)row_glob * (NC * NPD) + pp * NPD + j0;
            const f32x4 o0 = {o[0], o[1], o[2], o[3]};
            const f32x4 o1 = {o[4], o[5], o[6], o[7]};
            __builtin_nontemporal_store(o0, (f32x4*)og);
            __builtin_nontemporal_store(o1, (f32x4*)(og + 4));
        }
        if (p < 3) __syncthreads();
    }
}

extern "C" void kernel_launch(void* const* d_in, const int* in_sizes, int n_in,
                              void* d_out, int out_size, void* d_ws, size_t ws_size,
                              hipStream_t stream) {
    (void)in_sizes; (void)n_in; (void)ws_size; (void)out_size;
    const float* x  = (const float*)d_in[0];
    const float* Wp = (const float*)d_in[1];
    const float* bp = (const float*)d_in[2];
    const float* W  = (const float*)d_in[3];
    float* out = (float*)d_out;
    unsigned short* wpt = (unsigned short*)d_ws;   // 196608 B used

    caps_prep_wp<<<384, 256, 0, stream>>>(Wp, wpt);   // 98304 elements
    caps_main<<<BATCH / BM, 256, 0, stream>>>(x, bp, W, wpt, out);
}